// Round 6
// baseline (229.561 us; speedup 1.0000x reference)
//
#include <hip/hip_runtime.h>
#include <float.h>
#include <math.h>

#define B_SZ   2048
#define D_DIM  256
#define P_DIM  4
#define N_TOT  4096        // 2*B
#define EPS_F  1e-8f
#define RPP    16          // rows per panel (block)
#define NB     1024        // buckets per row histogram
#define HR     1025        // hist row stride (odd: +1 bank offset per row)
#define BSCALE 256.0f      // bucket width 1/256; tie-approx err ~1.3e-2 << 0.146

typedef short  s16x8 __attribute__((ext_vector_type(8)));
typedef float  f32x4 __attribute__((ext_vector_type(4)));

__device__ __forceinline__ unsigned short f2bf(float x) {
    unsigned int b = __float_as_uint(x);
    b += 0x7FFFu + ((b >> 16) & 1u);        // RNE
    return (unsigned short)(b >> 16);
}

// ---------------- Kernel A: row-normalize features -> bf16 ----------------
__global__ __launch_bounds__(64) void normalize_kernel(
    const float* __restrict__ z_i, const float* __restrict__ z_j,
    unsigned short* __restrict__ fb)
{
    int row  = blockIdx.x;
    int lane = threadIdx.x;
    const float* src = (row < B_SZ) ? (z_i + (size_t)row * D_DIM)
                                    : (z_j + (size_t)(row - B_SZ) * D_DIM);
    float4 v = ((const float4*)src)[lane];
    float ss = v.x*v.x + v.y*v.y + v.z*v.z + v.w*v.w;
    #pragma unroll
    for (int off = 32; off > 0; off >>= 1)
        ss += __shfl_down(ss, off, 64);
    ss = __shfl(ss, 0, 64);
    float inv = 1.0f / sqrtf(ss);
    ushort4 o;
    o.x = f2bf(v.x * inv); o.y = f2bf(v.y * inv);
    o.z = f2bf(v.z * inv); o.w = f2bf(v.w * inv);
    ((ushort4*)(fb + (size_t)row * D_DIM))[lane] = o;
}

// ---------------- Kernel B (FUSED): per-16-row-panel logits + bucket-CDF loss ----------------
// R0-R5 post-mortem: three structurally different row_kernels all ~100us (VALUBusy 17%,
// HBM 2%) and five gemm treatments all left a ~75us residual -> the producer/consumer
// 32MB logits round-trip IS the wall. This kernel never materializes logits: MFMA
// computes a 16x16 fp32 logit tile in registers, which feeds exp/bucket/atomicAdd into
// per-row LDS histograms directly. Pass 2 recomputes logits (MFMA is ~2us total) and
// accumulates log(denom)-logit. fb (2MB) is L2-resident; expected floor = per-XCD L2
// BW for ~1GB of B-fragment re-reads (~30us).
__global__ __launch_bounds__(512, 2) void panel_kernel(
    const unsigned short* __restrict__ fb,
    const float* __restrict__ physics_i, const float* __restrict__ physics_j,
    float* __restrict__ partial)
{
    __shared__ float hist[RPP * HR];         // 65.6 KB
    __shared__ float scr[8];

    int tid = threadIdx.x;
    int L   = tid & 63;
    int w   = tid >> 6;                      // 0..7
    int i0  = blockIdx.x * RPP;

    for (int t = tid; t < RPP * HR; t += 512) hist[t] = 0.f;

    // A-fragments: resident all kernel. Lane L holds row i0+(L&15),
    // k-chunk kc covers k = kc*32 + (L>>4)*8 .. +8  (proven layout from old gemm).
    s16x8 a[8];
    #pragma unroll
    for (int kc = 0; kc < 8; ++kc)
        a[kc] = *(const s16x8*)(fb + (size_t)(i0 + (L & 15)) * D_DIM
                                + kc * 32 + (L >> 4) * 8);

    // labels for this lane's 4 output rows (C-layout row = (L>>4)*4 + q)
    float4 Lr[4];
    #pragma unroll
    for (int q = 0; q < 4; ++q) {
        int r = i0 + (L >> 4) * 4 + q;
        const float* p = (r < B_SZ) ? physics_i + (size_t)r * P_DIM
                                    : physics_j + (size_t)(r - B_SZ) * P_DIM;
        Lr[q] = *(const float4*)p;
    }

    __syncthreads();                         // B0: zeros visible before atomics

    // ---- pass 1: build per-row histograms of exp(logit) keyed by label-distance ----
    for (int ct = 0; ct < 32; ++ct) {
        int c0 = ct * 128 + w * 16;          // 8 waves x 16 cols = 128 cols / iter
        int jc = c0 + (L & 15);

        s16x8 b[8];
        #pragma unroll
        for (int kc = 0; kc < 8; ++kc)
            b[kc] = *(const s16x8*)(fb + (size_t)jc * D_DIM + kc * 32 + (L >> 4) * 8);
        const float* pj = (jc < B_SZ) ? physics_i + (size_t)jc * P_DIM
                                      : physics_j + (size_t)(jc - B_SZ) * P_DIM;
        float4 Lj = *(const float4*)pj;

        f32x4 acc0 = {0.f, 0.f, 0.f, 0.f};  // two chains: halve MFMA dep latency
        f32x4 acc1 = {0.f, 0.f, 0.f, 0.f};
        #pragma unroll
        for (int kc = 0; kc < 4; ++kc) {
            acc0 = __builtin_amdgcn_mfma_f32_16x16x32_bf16(a[2*kc],   b[2*kc],   acc0, 0, 0, 0);
            acc1 = __builtin_amdgcn_mfma_f32_16x16x32_bf16(a[2*kc+1], b[2*kc+1], acc1, 0, 0, 0);
        }

        #pragma unroll
        for (int q = 0; q < 4; ++q) {
            int rq = (L >> 4) * 4 + q;
            float logit = (acc0[q] + acc1[q]) * 0.5f;      // /TEMP
            float d = fabsf(Lr[q].x - Lj.x) + fabsf(Lr[q].y - Lj.y)
                    + fabsf(Lr[q].z - Lj.z) + fabsf(Lr[q].w - Lj.w);
            int bk = (int)(d * BSCALE); if (bk > NB - 1) bk = NB - 1;
            if (jc != i0 + rq)
                atomicAdd(&hist[rq * HR + bk], __expf(logit));
        }
    }
    __syncthreads();                         // B1: histograms complete

    // ---- per-row inclusive suffix CDF; wave w owns rows 2w, 2w+1 (intra-wave) ----
    #pragma unroll
    for (int rr = 0; rr < 2; ++rr) {
        float* hrow = hist + (w * 2 + rr) * HR + L * 16;
        float v[16];
        float fs = 0.f;
        #pragma unroll
        for (int k = 0; k < 16; ++k) { v[k] = hrow[k]; fs += v[k]; }
        float s = fs;
        #pragma unroll
        for (int off = 1; off < 64; off <<= 1) {           // suffix: pull higher lanes
            float u = __shfl_down(s, off, 64);
            if (L + off < 64) s += u;
        }
        float run = s - fs;                  // sum of buckets strictly above lane's range
        #pragma unroll
        for (int k = 15; k >= 0; --k) { run += v[k]; hrow[k] = run; }
    }
    __syncthreads();                         // B2: CDF ready

    // ---- pass 2: recompute logits, accumulate log(denom) - logit ----
    float ACC = 0.f;
    for (int ct = 0; ct < 32; ++ct) {
        int c0 = ct * 128 + w * 16;
        int jc = c0 + (L & 15);

        s16x8 b[8];
        #pragma unroll
        for (int kc = 0; kc < 8; ++kc)
            b[kc] = *(const s16x8*)(fb + (size_t)jc * D_DIM + kc * 32 + (L >> 4) * 8);
        const float* pj = (jc < B_SZ) ? physics_i + (size_t)jc * P_DIM
                                      : physics_j + (size_t)(jc - B_SZ) * P_DIM;
        float4 Lj = *(const float4*)pj;

        f32x4 acc0 = {0.f, 0.f, 0.f, 0.f};
        f32x4 acc1 = {0.f, 0.f, 0.f, 0.f};
        #pragma unroll
        for (int kc = 0; kc < 4; ++kc) {
            acc0 = __builtin_amdgcn_mfma_f32_16x16x32_bf16(a[2*kc],   b[2*kc],   acc0, 0, 0, 0);
            acc1 = __builtin_amdgcn_mfma_f32_16x16x32_bf16(a[2*kc+1], b[2*kc+1], acc1, 0, 0, 0);
        }

        #pragma unroll
        for (int q = 0; q < 4; ++q) {
            int rq = (L >> 4) * 4 + q;
            float logit = (acc0[q] + acc1[q]) * 0.5f;
            float d = fabsf(Lr[q].x - Lj.x) + fabsf(Lr[q].y - Lj.y)
                    + fabsf(Lr[q].z - Lj.z) + fabsf(Lr[q].w - Lj.w);
            int bk = (int)(d * BSCALE); if (bk > NB - 1) bk = NB - 1;
            if (jc != i0 + rq)
                ACC += __logf(hist[rq * HR + bk] + EPS_F) - logit;
        }
    }

    // ---- block reduce ----
    #pragma unroll
    for (int off = 32; off > 0; off >>= 1)
        ACC += __shfl_down(ACC, off, 64);
    if (L == 0) scr[w] = ACC;
    __syncthreads();                         // B3
    if (tid == 0) {
        float s = 0.f;
        #pragma unroll
        for (int w2 = 0; w2 < 8; ++w2) s += scr[w2];
        partial[blockIdx.x] = s;
    }
}

// ---------------- Kernel C: final reduce (256 panel partials) ----------------
__global__ __launch_bounds__(256) void final_kernel(
    const float* __restrict__ partial, float* __restrict__ out)
{
    __shared__ float red[4];
    int tid = threadIdx.x;
    float s = 0.f;
    for (int i = tid; i < N_TOT / RPP; i += 256) s += partial[i];
    #pragma unroll
    for (int off = 32; off > 0; off >>= 1)
        s += __shfl_down(s, off, 64);
    if ((tid & 63) == 0) red[tid >> 6] = s;
    __syncthreads();
    if (tid == 0) {
        double tot = (double)red[0] + red[1] + red[2] + red[3];
        out[0] = (float)(tot / ((double)N_TOT * (N_TOT - 1)));
    }
}

extern "C" void kernel_launch(void* const* d_in, const int* in_sizes, int n_in,
                              void* d_out, int out_size, void* d_ws, size_t ws_size,
                              hipStream_t stream)
{
    const float* z_i  = (const float*)d_in[0];
    const float* z_j  = (const float*)d_in[1];
    const float* ph_i = (const float*)d_in[2];
    const float* ph_j = (const float*)d_in[3];

    unsigned short* fb      = (unsigned short*)d_ws;                  // 2 MB bf16
    float*          partial = (float*)(fb + (size_t)N_TOT * D_DIM);   // 1 KB

    normalize_kernel<<<N_TOT, 64, 0, stream>>>(z_i, z_j, fb);
    panel_kernel<<<N_TOT / RPP, 512, 0, stream>>>(fb, ph_i, ph_j, partial);
    final_kernel<<<1, 256, 0, stream>>>(partial, (float*)d_out);
}